// Round 20
// baseline (53.822 us; speedup 1.0000x reference)
//
#include <hip/hip_runtime.h>

#define EPS 1e-8f

__device__ __forceinline__ float sigmoidf_(float x) {
    return 1.0f / (1.0f + expf(-x));
}

// ---------------------------------------------------------------------------
// Two-kernel chunked scan (proven R17 structure) + INLINE-ASM nt stores.
//   k1  : thread (bf,c): deep-prefetch m[50] (plain loads, pinned by asm
//         clobber), zero-carry scan, store aggregate S[c][bf] (c < C-1).
//   emit: REVERSED chunk order (freshest-in-L3 first), parallel prefetch
//         m[50] + masked SS[19] (plain loads, pinned), Horner carry combine
//         (pure VALU), scan + normalize, then stores issued as
//         `global_store_dword ..., off nt` VIA INLINE ASM -- the
//         __builtin_nontemporal_store path breaks the prefetch codegen
//         (VGPR 100->44, R18/R19); opaque asm leaves regalloc untouched
//         while still setting the no-allocate cache bit so `out` lines
//         don't evict mag from L3 between k1 and emit.
// All loads wave-coalesced (consecutive threads = consecutive bf).
// ---------------------------------------------------------------------------

template <int L>
__global__ __launch_bounds__(256)
void fns20_aggregate(const float* __restrict__ mag,
                     const float* __restrict__ alpha,
                     float* __restrict__ S,   // [C-1][BF]
                     int B, int T, int F, int C1) {
    const int BF = B * F;
    int g = blockIdx.x * blockDim.x + threadIdx.x;
    if (g >= BF * C1) return;
    const int bf = g % BF;
    const int c  = g / BF;
    const int b  = bf / F;
    const int f  = bf - b * F;

    const float a   = sigmoidf_(alpha[f]);
    const float oma = 1.0f - a;

    const float* p = mag + ((size_t)b * T + (size_t)c * L) * F + f;

    // deep prefetch: all L loads issued before the recurrence
    float m[L];
#pragma unroll
    for (int t = 0; t < L; ++t)
        m[t] = p[(size_t)t * F];
    asm volatile("" ::: "memory");

    float local = 0.0f;
#pragma unroll
    for (int t = 0; t < L; ++t)
        local = local * oma + (m[t] * m[t]) * a;  // exact reference form
    S[(size_t)c * BF + bf] = local;
}

template <int L, int C>
__global__ __launch_bounds__(256)
void fns20_emit(const float* __restrict__ mag,
                const float* __restrict__ s0,
                const float* __restrict__ weights,
                const float* __restrict__ bias,
                const float* __restrict__ alpha,
                const float* __restrict__ S,   // [C-1][BF]
                float* __restrict__ out,
                int B, int T, int F) {
    const int BF = B * F;
    int g = blockIdx.x * blockDim.x + threadIdx.x;
    if (g >= BF * C) return;
    const int bf = g % BF;
    const int c  = C - 1 - (g / BF);   // reversed: freshest-in-L3 chunks first
    const int b  = bf / F;
    const int f  = bf - b * F;

    const float a   = sigmoidf_(alpha[f]);
    const float oma = 1.0f - a;
    const float w   = weights[f];
    const float bi  = bias[f];

    const float* p = mag + ((size_t)b * T + (size_t)c * L) * F + f;
    float*       o = out + ((size_t)b * T + (size_t)c * L) * F + f;

    // ---- deep prefetch 1: mag (plain loads) ----
    float m[L];
#pragma unroll
    for (int t = 0; t < L; ++t)
        m[t] = p[(size_t)t * F];

    // ---- deep prefetch 2: chunk aggregates (L2-hot), masked ----
    float SS[C - 1];
#pragma unroll
    for (int j = 0; j < C - 1; ++j)
        SS[j] = (j < c) ? S[(size_t)j * BF + bf] : 0.0f;
    asm volatile("" ::: "memory");   // pin all loads before first use

    // ---- carry combine: pure VALU, identical arithmetic to sequential pass
    float D = 1.0f;                  // (1-a)^L via product
#pragma unroll
    for (int i = 0; i < L; ++i) D *= oma;
    float carry = s0[bf];
#pragma unroll
    for (int j = 0; j < C - 1; ++j)
        carry = (j < c) ? (carry * D + SS[j]) : carry;

    // ---- scan + normalize + inline-asm non-temporal store ----
#pragma unroll
    for (int t = 0; t < L; ++t) {
        carry = carry * oma + (m[t] * m[t]) * a;
        // 1/(sqrt+eps) via hw rcp (~1 ulp); bounded output -> abs err ~1e-6
        float r = m[t] * __builtin_amdgcn_rcpf(sqrtf(carry) + EPS) * w + bi;
        const float* addr = o + (size_t)t * F;
        asm volatile("global_store_dword %0, %1, off nt"
                     :: "v"(addr), "v"(r));
    }
}

// Generic emit (runtime C) -- proven R11 form, for non-standard shapes.
template <int L>
__global__ __launch_bounds__(256)
void fns11_emit(const float* __restrict__ mag,
                const float* __restrict__ s0,
                const float* __restrict__ weights,
                const float* __restrict__ bias,
                const float* __restrict__ alpha,
                const float* __restrict__ S,
                float* __restrict__ out,
                int B, int T, int F, int C) {
    const int BF = B * F;
    int g = blockIdx.x * blockDim.x + threadIdx.x;
    if (g >= BF * C) return;
    const int bf = g % BF;
    const int c  = g / BF;
    const int b  = bf / F;
    const int f  = bf - b * F;

    const float a   = sigmoidf_(alpha[f]);
    const float oma = 1.0f - a;
    const float w   = weights[f];
    const float bi  = bias[f];

    float carry = s0[bf];
    if (c > 0) {
        float D = 1.0f;
#pragma unroll
        for (int i = 0; i < L; ++i) D *= oma;
        for (int j = 0; j < c; ++j)
            carry = carry * D + S[(size_t)j * BF + bf];
    }

    const float* p = mag + ((size_t)b * T + (size_t)c * L) * F + f;
    float*       o = out + ((size_t)b * T + (size_t)c * L) * F + f;

    float m[L];
#pragma unroll
    for (int t = 0; t < L; ++t)
        m[t] = p[(size_t)t * F];
    asm volatile("" ::: "memory");

#pragma unroll
    for (int t = 0; t < L; ++t) {
        carry = carry * oma + (m[t] * m[t]) * a;
        o[(size_t)t * F] = m[t] * __builtin_amdgcn_rcpf(sqrtf(carry) + EPS) * w + bi;
    }
}

__global__ void fns_fallback(const float* __restrict__ mag,
                             const float* __restrict__ s0,
                             const float* __restrict__ weights,
                             const float* __restrict__ bias,
                             const float* __restrict__ alpha,
                             float* __restrict__ out,
                             int B, int T, int F) {
    int bf = blockIdx.x * blockDim.x + threadIdx.x;
    int BF = B * F;
    if (bf >= BF) return;
    int b = bf / F;
    int f = bf - b * F;

    float a  = sigmoidf_(alpha[f]);
    float w  = weights[f];
    float bi = bias[f];

    float carry = s0[bf];
    const float* p = mag + (size_t)b * T * F + f;
    float*       o = out + (size_t)b * T * F + f;

    for (int t = 0; t < T; ++t) {
        float m = p[(size_t)t * F];
        carry = carry * (1.0f - a) + (m * m) * a;
        o[(size_t)t * F] = m / (sqrtf(carry) + EPS) * w + bi;
    }
}

extern "C" void kernel_launch(void* const* d_in, const int* in_sizes, int n_in,
                              void* d_out, int out_size, void* d_ws, size_t ws_size,
                              hipStream_t stream) {
    const float* mag     = (const float*)d_in[0];
    const float* s0      = (const float*)d_in[1];
    const float* weights = (const float*)d_in[2];
    const float* bias    = (const float*)d_in[3];
    const float* alpha   = (const float*)d_in[4];
    float* out = (float*)d_out;

    int F  = in_sizes[4];          // alpha is [1, F]
    int BF = in_sizes[1];          // s is [B, F]
    int B  = BF / F;
    int T  = in_sizes[0] / BF;     // mag is [B, T, F]

    constexpr int L = 50;          // chunk length (compile-time, full unroll)
    if (T % L == 0) {
        int C  = T / L;            // 20 for T=1000
        int C1 = C - 1;
        size_t need = (size_t)C1 * BF * sizeof(float);
        if (C1 >= 1 && ws_size >= need) {
            float* S = (float*)d_ws;
            int n1 = BF * C1;                    // 312,512
            int n2 = BF * C;                     // 328,960
            fns20_aggregate<L><<<(n1 + 255) / 256, 256, 0, stream>>>(
                mag, alpha, S, B, T, F, C1);
            if (C == 20) {
                fns20_emit<L, 20><<<(n2 + 255) / 256, 256, 0, stream>>>(
                    mag, s0, weights, bias, alpha, S, out, B, T, F);
            } else {
                fns11_emit<L><<<(n2 + 255) / 256, 256, 0, stream>>>(
                    mag, s0, weights, bias, alpha, S, out, B, T, F, C);
            }
            return;
        }
    }

    int threads = 256;
    int blocks  = (BF + threads - 1) / threads;
    fns_fallback<<<blocks, threads, 0, stream>>>(mag, s0, weights, bias,
                                                 alpha, out, B, T, F);
}

// Round 21
// 43.021 us; speedup vs baseline: 1.2511x; 1.2511x over previous
//
#include <hip/hip_runtime.h>

#define EPS 1e-8f

__device__ __forceinline__ float sigmoidf_(float x) {
    return 1.0f / (1.0f + expf(-x));
}

// ---------------------------------------------------------------------------
// FINAL (reverted to measured-best R17, 42.2 us):
// Two-kernel chunked scan. Chains (b,f) as bf in [0,BF); time in C chunks
// of L=50. Thread (bf,c); consecutive threads = consecutive bf -> every
// load/store is a wave-coalesced 256 B transaction.
//   k1  : deep-prefetch m[50] (plain loads, pinned live by asm memory
//         clobber -> ~50 loads in flight/wave), zero-carry scan, store
//         chunk aggregate S[c][bf] (c < C-1; S[C-1] never consumed).
//   emit: REVERSED chunk order (freshest-in-L3 chunks first), parallel
//         prefetch m[50] + masked SS[19] (dependent-load chain converted
//         to parallel batch), Horner carry combine in pure VALU
//         (arithmetically identical to a sequential middle pass), scan +
//         normalize (hw rcp) + plain cached stores.
// Known-dead ends (measured): LDS staging panels (-populated occupancy),
// decoupled lookback & cooperative grid-sync (cross-XCD sync >100us),
// float2 width (halves TLP), 3-kernel prefix, block-fused single pass
// (phase serialization), hierarchical half-chunks, and ALL non-temporal
// paths (builtin & inline-asm: each collapses the m[50] live range,
// VGPR ~100 -> 44-56, breaking the deep prefetch).
// ---------------------------------------------------------------------------

template <int L>
__global__ __launch_bounds__(256)
void fns17_aggregate(const float* __restrict__ mag,
                     const float* __restrict__ alpha,
                     float* __restrict__ S,   // [C-1][BF]
                     int B, int T, int F, int C1) {
    const int BF = B * F;
    int g = blockIdx.x * blockDim.x + threadIdx.x;
    if (g >= BF * C1) return;
    const int bf = g % BF;
    const int c  = g / BF;
    const int b  = bf / F;
    const int f  = bf - b * F;

    const float a   = sigmoidf_(alpha[f]);
    const float oma = 1.0f - a;

    const float* p = mag + ((size_t)b * T + (size_t)c * L) * F + f;

    // deep prefetch: all L loads issued before the recurrence
    float m[L];
#pragma unroll
    for (int t = 0; t < L; ++t)
        m[t] = p[(size_t)t * F];
    asm volatile("" ::: "memory");

    float local = 0.0f;
#pragma unroll
    for (int t = 0; t < L; ++t)
        local = local * oma + (m[t] * m[t]) * a;  // exact reference form
    S[(size_t)c * BF + bf] = local;
}

template <int L, int C>
__global__ __launch_bounds__(256)
void fns17_emit(const float* __restrict__ mag,
                const float* __restrict__ s0,
                const float* __restrict__ weights,
                const float* __restrict__ bias,
                const float* __restrict__ alpha,
                const float* __restrict__ S,   // [C-1][BF]
                float* __restrict__ out,
                int B, int T, int F) {
    const int BF = B * F;
    int g = blockIdx.x * blockDim.x + threadIdx.x;
    if (g >= BF * C) return;
    const int bf = g % BF;
    const int c  = C - 1 - (g / BF);   // reversed: freshest-in-L3 chunks first
    const int b  = bf / F;
    const int f  = bf - b * F;

    const float a   = sigmoidf_(alpha[f]);
    const float oma = 1.0f - a;
    const float w   = weights[f];
    const float bi  = bias[f];

    const float* p = mag + ((size_t)b * T + (size_t)c * L) * F + f;
    float*       o = out + ((size_t)b * T + (size_t)c * L) * F + f;

    // ---- deep prefetch 1: mag (HBM/L3, longest latency) ----
    float m[L];
#pragma unroll
    for (int t = 0; t < L; ++t)
        m[t] = p[(size_t)t * F];

    // ---- deep prefetch 2: chunk aggregates (L2-resident), masked ----
    float SS[C - 1];
#pragma unroll
    for (int j = 0; j < C - 1; ++j)
        SS[j] = (j < c) ? S[(size_t)j * BF + bf] : 0.0f;
    asm volatile("" ::: "memory");   // pin all loads before first use

    // ---- carry combine: pure VALU, identical arithmetic to sequential pass
    float D = 1.0f;                  // (1-a)^L via product
#pragma unroll
    for (int i = 0; i < L; ++i) D *= oma;
    float carry = s0[bf];
#pragma unroll
    for (int j = 0; j < C - 1; ++j)
        carry = (j < c) ? (carry * D + SS[j]) : carry;

    // ---- scan + normalize + store ----
#pragma unroll
    for (int t = 0; t < L; ++t) {
        carry = carry * oma + (m[t] * m[t]) * a;
        // 1/(sqrt+eps) via hw rcp (~1 ulp); bounded output -> abs err ~1e-6
        o[(size_t)t * F] = m[t] * __builtin_amdgcn_rcpf(sqrtf(carry) + EPS) * w + bi;
    }
}

// Generic emit (runtime C) -- for non-standard shapes.
template <int L>
__global__ __launch_bounds__(256)
void fns11_emit(const float* __restrict__ mag,
                const float* __restrict__ s0,
                const float* __restrict__ weights,
                const float* __restrict__ bias,
                const float* __restrict__ alpha,
                const float* __restrict__ S,
                float* __restrict__ out,
                int B, int T, int F, int C) {
    const int BF = B * F;
    int g = blockIdx.x * blockDim.x + threadIdx.x;
    if (g >= BF * C) return;
    const int bf = g % BF;
    const int c  = g / BF;
    const int b  = bf / F;
    const int f  = bf - b * F;

    const float a   = sigmoidf_(alpha[f]);
    const float oma = 1.0f - a;
    const float w   = weights[f];
    const float bi  = bias[f];

    float carry = s0[bf];
    if (c > 0) {
        float D = 1.0f;
#pragma unroll
        for (int i = 0; i < L; ++i) D *= oma;
        for (int j = 0; j < c; ++j)
            carry = carry * D + S[(size_t)j * BF + bf];
    }

    const float* p = mag + ((size_t)b * T + (size_t)c * L) * F + f;
    float*       o = out + ((size_t)b * T + (size_t)c * L) * F + f;

    float m[L];
#pragma unroll
    for (int t = 0; t < L; ++t)
        m[t] = p[(size_t)t * F];
    asm volatile("" ::: "memory");

#pragma unroll
    for (int t = 0; t < L; ++t) {
        carry = carry * oma + (m[t] * m[t]) * a;
        o[(size_t)t * F] = m[t] * __builtin_amdgcn_rcpf(sqrtf(carry) + EPS) * w + bi;
    }
}

__global__ void fns_fallback(const float* __restrict__ mag,
                             const float* __restrict__ s0,
                             const float* __restrict__ weights,
                             const float* __restrict__ bias,
                             const float* __restrict__ alpha,
                             float* __restrict__ out,
                             int B, int T, int F) {
    int bf = blockIdx.x * blockDim.x + threadIdx.x;
    int BF = B * F;
    if (bf >= BF) return;
    int b = bf / F;
    int f = bf - b * F;

    float a  = sigmoidf_(alpha[f]);
    float w  = weights[f];
    float bi = bias[f];

    float carry = s0[bf];
    const float* p = mag + (size_t)b * T * F + f;
    float*       o = out + (size_t)b * T * F + f;

    for (int t = 0; t < T; ++t) {
        float m = p[(size_t)t * F];
        carry = carry * (1.0f - a) + (m * m) * a;
        o[(size_t)t * F] = m / (sqrtf(carry) + EPS) * w + bi;
    }
}

extern "C" void kernel_launch(void* const* d_in, const int* in_sizes, int n_in,
                              void* d_out, int out_size, void* d_ws, size_t ws_size,
                              hipStream_t stream) {
    const float* mag     = (const float*)d_in[0];
    const float* s0      = (const float*)d_in[1];
    const float* weights = (const float*)d_in[2];
    const float* bias    = (const float*)d_in[3];
    const float* alpha   = (const float*)d_in[4];
    float* out = (float*)d_out;

    int F  = in_sizes[4];          // alpha is [1, F]
    int BF = in_sizes[1];          // s is [B, F]
    int B  = BF / F;
    int T  = in_sizes[0] / BF;     // mag is [B, T, F]

    constexpr int L = 50;          // chunk length (compile-time, full unroll)
    if (T % L == 0) {
        int C  = T / L;            // 20 for T=1000
        int C1 = C - 1;
        size_t need = (size_t)C1 * BF * sizeof(float);
        if (C1 >= 1 && ws_size >= need) {
            float* S = (float*)d_ws;
            int n1 = BF * C1;                    // 312,512
            int n2 = BF * C;                     // 328,960
            fns17_aggregate<L><<<(n1 + 255) / 256, 256, 0, stream>>>(
                mag, alpha, S, B, T, F, C1);
            if (C == 20) {
                fns17_emit<L, 20><<<(n2 + 255) / 256, 256, 0, stream>>>(
                    mag, s0, weights, bias, alpha, S, out, B, T, F);
            } else {
                fns11_emit<L><<<(n2 + 255) / 256, 256, 0, stream>>>(
                    mag, s0, weights, bias, alpha, S, out, B, T, F, C);
            }
            return;
        }
    }

    int threads = 256;
    int blocks  = (BF + threads - 1) / threads;
    fns_fallback<<<blocks, threads, 0, stream>>>(mag, s0, weights, bias,
                                                 alpha, out, B, T, F);
}